// Round 1
// baseline (202.600 us; speedup 1.0000x reference)
//
#include <hip/hip_runtime.h>
#include <math.h>

#define HH 1024
#define WW 1024
#define NPLANES 12              // B*C = 4*3
#define PLANE (HH * WW)

#define TW 64                   // output tile width
#define TH 64                   // output tile height
#define RROWS 92                // rows staged: gy in [y0-14, y0+77]
#define PA 96                   // A pitch/cols: gx in [x0-16, x0+79], quad-XOR swizzled
#define PB 80                   // h1 pitch: gx in [x0-8, x0+71]
#define P1 80                   // B1 pitch (lives in A-space)
#define PC 64                   // h2 pitch (lives in B-space)

struct W15 { float w[15]; };

__device__ inline float chain1(float t, float gain, float gamma, float sb,
                               float hr, float br, float ct) {
    t = t * gain;
    t = __builtin_amdgcn_exp2f(gamma * __log2f(t));          // pow(t,gamma), t>=0
    float hi = __fdividef(1.0f, 1.0f + __expf((0.5f - t) * 10.0f));
    t = t + sb * (1.0f - hi) - hr * hi;
    t = fminf(fmaxf(t, 0.0f), 1.0f);
    t = ct * (t - 0.5f) + 0.5f + br;
    return fminf(fmaxf(t, 0.0f), 1.0f);
}

// 15-tap horizontal dot, 4 outputs, two accumulator trees per output.
// f[0] corresponds to input col (4*j4); outputs are cols (4*j4 + j) shifted by +8
// relative to the input base (i.e. input range f[j+1 .. j+15]).
__device__ inline float4 hdot4(const float* f, const W15& wk) {
    float4 o; float* po = (float*)&o;
#pragma unroll
    for (int j = 0; j < 4; ++j) {
        float a = 0.0f, b = 0.0f;
#pragma unroll
        for (int k = 0; k < 8; ++k)  a += wk.w[k] * f[j + 1 + k];
#pragma unroll
        for (int k = 8; k < 15; ++k) b += wk.w[k] * f[j + 1 + k];
        po[j] = a + b;
    }
    return o;
}

__device__ inline float dot15(const float* win, const W15& wk) {
    float a = 0.0f, b = 0.0f;
#pragma unroll
    for (int k = 0; k < 8; ++k)  a += wk.w[k] * win[k];
#pragma unroll
    for (int k = 8; k < 15; ++k) b += wk.w[k] * win[k];
    return a + b;
}

// ---- XCD-aware tile remap: same-XCD (mod-8) blocks cover contiguous region ---
__device__ inline void tile_map(int& p, int& x0, int& y0, bool& edge) {
    int L = (blockIdx.z * gridDim.y + blockIdx.y) * gridDim.x + blockIdx.x; // 0..3071
    int xcd = L & 7;
    int t   = L >> 3;                 // 0..383
    int g   = xcd * 384 + t;          // contiguous 1.5-plane region per XCD
    p = g >> 8;                       // /256 tiles per plane
    int w  = g & 255;
    int ty = w >> 4, tx = w & 15;
    x0 = tx * TW; y0 = ty * TH;
    edge = (tx == 0) || (tx == 15) || (ty == 0) || (ty == 15);
}

// =============================================================================
// Fully fused: chain -> B(x1) -> B(B(x1)) in LDS -> combine -> mask -> out
// out = s*((1+e)B1 - e*B2) + (1-s)*((1+e)x1 - e*B1), then gradient mask + clip
// =============================================================================
__global__ __launch_bounds__(256) void k_fused(
    const float* __restrict__ x, float* __restrict__ dst,
    const float* __restrict__ gains,
    const float* __restrict__ pg, const float* __restrict__ psb,
    const float* __restrict__ phr, const float* __restrict__ pbr,
    const float* __restrict__ pct, const float* __restrict__ penh,
    const float* __restrict__ psoft, const float* __restrict__ pint,
    const float* __restrict__ prot, const float* __restrict__ phard,
    W15 wk)
{
    __shared__ float A [RROWS * PA];   // 35328 B : x1 region, later B1 (pitch 80)
    __shared__ float Bb[RROWS * PB];   // 29440 B : h1, later h2 (pitch 64)

    int p, x0, y0; bool edge;
    tile_map(p, x0, y0, edge);
    const int tid = threadIdx.x;
    const int tx  = tid & 63;
    const int ty  = tid >> 6;

    const float* __restrict__ plane = x + (size_t)p * PLANE;
    const float gain  = gains[p % 3];
    const float gamma = *pg, sb = *psb, hr = *phr, br = *pbr, ct = *pct;

    // ---------------- Phase 1: chain(x) over 92x96 halo region -> A ----------
    // A quad-XOR swizzle: float4 quad q of row r stored at quad (q ^ (r&7)).
    // (PA=96 == 0 mod 32 banks; swizzle de-aliases rows within a wave.)
    if (!edge) {
        const float* base = plane + (size_t)(y0 - 14) * WW + (x0 - 16);
        auto do1 = [&](int c) {
            int r = c / 24, c4 = c % 24;
            float4 v = *(const float4*)(base + (size_t)r * WW + 4 * c4);
            float* pv = (float*)&v;
#pragma unroll
            for (int q = 0; q < 4; ++q)
                pv[q] = chain1(pv[q], gain, gamma, sb, hr, br, ct);
            *(float4*)&A[r * PA + ((c4 ^ (r & 7)) << 2)] = v;
        };
#pragma unroll
        for (int it = 0; it < 8; ++it) do1(tid + 256 * it);     // c <= 2047 < 2208
        if (tid < 160) do1(tid + 2048);                         // tail
    } else {
        auto do1e = [&](int c) {
            int r = c / 24, c4 = c % 24;
            int gy  = y0 - 14 + r;
            int gx0 = x0 - 16 + 4 * c4;
            float4 v = make_float4(0.f, 0.f, 0.f, 0.f);
            if ((unsigned)gy < HH) {
                const float* row = plane + (size_t)gy * WW;
                float* pv = (float*)&v;
                if (gx0 >= 0 && gx0 + 3 < WW) {
                    v = *(const float4*)(row + gx0);
#pragma unroll
                    for (int q = 0; q < 4; ++q)
                        pv[q] = chain1(pv[q], gain, gamma, sb, hr, br, ct);
                } else {
#pragma unroll
                    for (int q = 0; q < 4; ++q) {
                        int gx = gx0 + q;
                        if ((unsigned)gx < WW)
                            pv[q] = chain1(row[gx], gain, gamma, sb, hr, br, ct);
                    }
                }
            }
            *(float4*)&A[r * PA + ((c4 ^ (r & 7)) << 2)] = v;
        };
#pragma unroll
        for (int it = 0; it < 8; ++it) do1e(tid + 256 * it);
        if (tid < 160) do1e(tid + 2048);
    }
    __syncthreads();

    // ---------------- Phase 2: cc = center x1 (regs); h1 = hblur(A) -> Bb -----
    float cc[16];
#pragma unroll
    for (int j = 0; j < 16; ++j) {
        int rr = ty * 16 + j + 14;                      // gy = y0 + ty*16 + j
        cc[j] = A[rr * PA + ((((tx >> 2) + 4) ^ (rr & 7)) << 2) + (tx & 3)];
    }
    {
        auto do2 = [&](int c) {
            int r = c / 20, j4 = c % 20;                // out cols gx = x0-8+4*j4+..
            int rx = r & 7;
            float f[20];
#pragma unroll
            for (int i = 0; i < 5; ++i)
                *(float4*)&f[4 * i] =
                    *(const float4*)&A[r * PA + (((j4 + i) ^ rx) << 2)];
            *(float4*)&Bb[r * PB + 4 * j4] = hdot4(f, wk);
        };
#pragma unroll
        for (int it = 0; it < 7; ++it) do2(tid + 256 * it);     // c <= 1791 < 1840
        if (tid < 48) do2(tid + 1792);                          // tail
    }
    __syncthreads();

    // ---------------- Phase 3: B1 = vblur(h1) (78x80) -> A-space --------------
    // B1 row r1 <-> gy = y0-7+r1 ; col j <-> gx = x0-8+j. Zero outside image
    // (required so the second blur sees zero-padded x2 components).
    float* B1 = A;
    if (tid < 240) {
        int j    = tid % 80;
        int band = tid / 80;                 // 3 bands x 26 rows = 78
        int r1s  = band * 26;
        bool xin = (unsigned)(x0 - 8 + j) < WW;
        float win[15];
#pragma unroll
        for (int k = 0; k < 14; ++k) win[k] = Bb[(r1s + k) * PB + j];
#pragma unroll
        for (int jj = 0; jj < 26; ++jj) {
            win[14] = Bb[(r1s + jj + 14) * PB + j];
            float v = dot15(win, wk);
            if (edge) {
                int gy = y0 - 7 + r1s + jj;
                if (!((unsigned)gy < HH) || !xin) v = 0.0f;
            }
            B1[(r1s + jj) * P1 + j] = v;
#pragma unroll
            for (int k = 0; k < 14; ++k) win[k] = win[k + 1];
        }
    }
    __syncthreads();

    // ---------------- Phase 4: bb = center B1 (regs); h2 = hblur(B1) -> Bb ----
    float bb[16];
#pragma unroll
    for (int j = 0; j < 16; ++j)
        bb[j] = B1[(ty * 16 + j + 7) * P1 + (tx + 8)];
    float* C = Bb;
    {
        auto do4 = [&](int c) {
            int r = c >> 4, j4 = c & 15;                // out cols gx = x0+4*j4+..
            float f[20];
#pragma unroll
            for (int i = 0; i < 5; ++i)
                *(float4*)&f[4 * i] = *(const float4*)&B1[r * P1 + 4 * (j4 + i)];
            *(float4*)&C[r * PC + 4 * j4] = hdot4(f, wk);
        };
#pragma unroll
        for (int it = 0; it < 4; ++it) do4(tid + 256 * it);     // c <= 1023 < 1248
        if (tid < 224) do4(tid + 1024);                         // tail
    }
    __syncthreads();

    // ---------------- Phase 5: B2 = vblur(h2); combine + mask + clip + store --
    const float e     = *penh;
    const float s     = *psoft;
    const float inten = *pint;
    const float hard  = *phard;
    const float theta = (*prot) * 0.017453292519943295f;
    const float cth = __cosf(theta), sth = __sinf(theta);
    const int   gx    = x0 + tx;
    const float gbase = (-1.0f + 2.0f * (float)gx * (1.0f / (float)(WW - 1))) * cth;
    const float ce    = 1.0f + e;

    float win[15];
#pragma unroll
    for (int k = 0; k < 14; ++k) win[k] = C[(ty * 16 + k) * PC + tx];

    float* __restrict__ dstP = dst + (size_t)p * PLANE;
#pragma unroll
    for (int jj = 0; jj < 16; ++jj) {
        win[14] = C[(ty * 16 + jj + 14) * PC + tx];
        float B2  = dot15(win, wk);
        float x2c = ce * cc[jj] - e * bb[jj];       // x2 at center
        float bx2 = ce * bb[jj] - e * B2;           // blur(x2) at center (linearity)
        float v   = s * bx2 + (1.0f - s) * x2c;
        int   y   = y0 + ty * 16 + jj;
        float gyn = -1.0f + 2.0f * (float)y * (1.0f / (float)(HH - 1));
        float mask = __fdividef(1.0f, 1.0f + __expf(hard * (gbase + gyn * sth)));
        v = v * (1.0f - inten * mask);
        v = fminf(fmaxf(v, 0.0f), 1.0f);
        dstP[(size_t)y * WW + gx] = v;
#pragma unroll
        for (int k = 0; k < 14; ++k) win[k] = win[k + 1];
    }
}

extern "C" void kernel_launch(void* const* d_in, const int* in_sizes, int n_in,
                              void* d_out, int out_size, void* d_ws, size_t ws_size,
                              hipStream_t stream)
{
    const float* x       = (const float*)d_in[0];
    const float* gains   = (const float*)d_in[1];
    const float* p_gamma = (const float*)d_in[2];
    const float* p_sb    = (const float*)d_in[3];
    const float* p_hr    = (const float*)d_in[4];
    const float* p_br    = (const float*)d_in[5];
    const float* p_ct    = (const float*)d_in[6];
    const float* p_enh   = (const float*)d_in[7];
    const float* p_soft  = (const float*)d_in[8];
    const float* p_int   = (const float*)d_in[9];
    const float* p_rot   = (const float*)d_in[10];
    const float* p_hard  = (const float*)d_in[11];

    W15 wk;
    {
        double g[15], sum = 0.0;
        for (int i = 0; i < 15; ++i) { double d = (double)(i - 7); g[i] = exp(-d * d / 18.0); sum += g[i]; }
        for (int i = 0; i < 15; ++i) wk.w[i] = (float)(g[i] / sum);
    }

    dim3 grid(WW / TW, HH / TH, NPLANES);   // 16 x 16 x 12 (remapped in-kernel)
    k_fused<<<grid, dim3(256), 0, stream>>>(
        x, (float*)d_out, gains, p_gamma, p_sb, p_hr, p_br, p_ct,
        p_enh, p_soft, p_int, p_rot, p_hard, wk);
}